// Round 17
// baseline (311.753 us; speedup 1.0000x reference)
//
#include <hip/hip_runtime.h>
#include <hip/hip_bf16.h>

typedef __attribute__((ext_vector_type(8))) short s16x8;
typedef __attribute__((ext_vector_type(4))) float f32x4;

#define NSLOT 128
#define CTR_OFF (NSLOT * 257)              // completion counter (int) after slots

__device__ __forceinline__ short f2bf(float f) {
    union { float f; unsigned u; } c; c.f = f;
    unsigned u = c.u;
    return (short)((u + 0x7fffu + ((u >> 16) & 1u)) >> 16);  // RNE
}
__device__ __forceinline__ unsigned pk2(float lo, float hi) {
    __hip_bfloat162 p = __float22bfloat162_rn(make_float2(lo, hi));
    return *reinterpret_cast<unsigned*>(&p);
}
// sum over the 16-lane DPP row via row_ror butterfly (VALU only, no DS pipe)
__device__ __forceinline__ float rowsum16(float x) {
    union { float f; int i; } a, b;
    a.f = x;
    b.i = __builtin_amdgcn_mov_dpp(a.i, 0x121, 0xf, 0xf, true); a.f += b.f; // ror:1
    b.i = __builtin_amdgcn_mov_dpp(a.i, 0x122, 0xf, 0xf, true); a.f += b.f; // ror:2
    b.i = __builtin_amdgcn_mov_dpp(a.i, 0x124, 0xf, 0xf, true); a.f += b.f; // ror:4
    b.i = __builtin_amdgcn_mov_dpp(a.i, 0x128, 0xf, 0xf, true); a.f += b.f; // ror:8
    return a.f;
}

// ---------------------------------------------------------------------------
// K1: precompute (unchanged, proven). Also zeroes the completion counter.
// ---------------------------------------------------------------------------
__global__ __launch_bounds__(256) void rn_k1(
    const float* __restrict__ x, const float* __restrict__ q,
    const float* __restrict__ g_w1, const float* __restrict__ g_b1,
    const float* __restrict__ g_w2,
    const float* __restrict__ qe_w1, const float* __restrict__ qe_b1,
    const float* __restrict__ qe_w2, const float* __restrict__ qe_b2,
    float* __restrict__ U, float* __restrict__ V,
    float* __restrict__ c0, float* __restrict__ qexp,
    short* __restrict__ w2s, float* __restrict__ accb)
{
    const int blk = blockIdx.x, t = threadIdx.x;

    if (blk < 64) {
        __shared__ float xs[1024];          // 16 rows x 64
        const int rg = blk >> 1, half = blk & 1;
        const int r0 = rg << 4;
        #pragma unroll
        for (int i = 0; i < 4; ++i) {
            int idx = i * 256 + t;
            xs[idx] = x[(r0 << 6) + idx];
        }
        float w[64];
        #pragma unroll
        for (int k = 0; k < 64; ++k)
            w[k] = g_w1[(half * 64 + k) * 256 + t];
        __syncthreads();
        float* dst = half ? V : U;
        #pragma unroll 2
        for (int r = 0; r < 16; ++r) {
            float a0 = 0.f, a1 = 0.f, a2 = 0.f, a3 = 0.f;
            #pragma unroll
            for (int k = 0; k < 64; k += 4) {
                const float4 xv = *(const float4*)&xs[r * 64 + k];
                a0 += xv.x * w[k + 0];
                a1 += xv.y * w[k + 1];
                a2 += xv.z * w[k + 2];
                a3 += xv.w * w[k + 3];
            }
            dst[(r0 + r) * 256 + t] = (a0 + a1) + (a2 + a3);
        }
    } else if (blk == 64) {
        __shared__ float sbuf[64];
        __shared__ float qh[256];
        if (t < 64) sbuf[t] = q[t];
        __syncthreads();
        float cc = g_b1[t], hh = qe_b1[t];
        #pragma unroll 4
        for (int k = 0; k < 64; ++k) {
            float qv = sbuf[k];
            cc += qv * g_w1[(128 + k) * 256 + t];
            hh += qv * qe_w1[k * 256 + t];
        }
        c0[t] = cc;
        qh[t] = fmaxf(hh, 0.f);
        __syncthreads();
        float qe = qe_b2[t];
        #pragma unroll 4
        for (int k = 0; k < 256; ++k) qe += qh[k] * qe_w2[k * 256 + t];
        qexp[t] = fmaxf(qe, 0.f);
    } else if (blk < 97) {
        const int S0 = (blk - 65) * 2048 + t * 8;
        const float4 wA = *(const float4*)&g_w2[S0];
        const float4 wB = *(const float4*)&g_w2[S0 + 4];
        float wv8[8] = {wA.x, wA.y, wA.z, wA.w, wB.x, wB.y, wB.z, wB.w};
        #pragma unroll
        for (int i = 0; i < 8; ++i) {
            const int S = S0 + i;
            const int k = S >> 8, col = S & 255;
            const int wv = col >> 6, n = (col >> 4) & 3, l15 = col & 15;
            const int kk = k >> 5, g = (k >> 3) & 3, e = k & 7;
            const int lane = g * 16 + l15;
            w2s[((((wv * 8 + kk) * 4 + n) * 64 + lane) << 3) + e] = f2bf(wv8[i]);
        }
    } else {
        const int total = NSLOT * 257 + 1;  // slots + completion counter
        int off = (blk - 97) * 2048 + t * 8;
        #pragma unroll
        for (int i = 0; i < 8; ++i)
            if (off + i < total) accb[off + i] = 0.f;
    }
}

// ---------------------------------------------------------------------------
// K2: R16 body (4096 blocks, 1 unit, launch_bounds(256,4), XOR-swizzled hT,
// 2 barriers, per-unit atomics, packed math) + FUSED FINAL MLP:
// after its atomics, each block does release-fence + counter atomic; the
// last block acquire-fences (cache-inv -> fresh accb across XCDs) and runs
// the 256-thread f-MLP inline, writing out[64]. One fewer kernel launch.
// ---------------------------------------------------------------------------
__global__ __launch_bounds__(256, 4) void rn_k2(
    const float* __restrict__ U, const float* __restrict__ V,
    const float* __restrict__ c0, const float* __restrict__ qexp,
    const short* __restrict__ w2s, const float* __restrict__ g_b2,
    float* __restrict__ accb,
    const float* __restrict__ f_w1, const float* __restrict__ f_b1,
    const float* __restrict__ f_w2, const float* __restrict__ f_b2,
    float* __restrict__ out)
{
    __shared__ short hT[16384];            // 32KB, XOR-swizzled image
    __shared__ float srowT[64][4];         // [row][wave]
    __shared__ float emb[256];
    __shared__ float fh[256];
    __shared__ int   lastFlag;

    const int bid = blockIdx.x;
    const int a   = bid >> 3;
    const int b0  = (bid & 7) << 6;
    const int tid = threadIdx.x;
    const int wave = tid >> 6, lane = tid & 63;
    const int l15 = lane & 15, g = lane >> 4;
    const int col0 = wave << 6;

    const f32x4 zero4 = (f32x4){0.f, 0.f, 0.f, 0.f};

    float qe[4], b2c[4];
    #pragma unroll
    for (int n = 0; n < 4; ++n) {
        int col = col0 + n * 16 + l15;
        qe[n]  = qexp[col];
        b2c[n] = g_b2[col];
    }

    // ---- build h tile: 64 rows x 256 cols (bf16, swizzled) ----
    {
        const int c4 = tid & 63;
        const int r0 = tid >> 6;
        const f32x4 vv  = *(const f32x4*)&V[a * 256 + c4 * 4];
        const f32x4 cc  = *(const f32x4*)&c0[c4 * 4];
        const f32x4 vcv = vv + cc;
        #pragma unroll
        for (int it = 0; it < 16; ++it) {
            const int row = r0 + it * 4;
            const f32x4 uu = *(const f32x4*)&U[(b0 + row) * 256 + c4 * 4];
            const f32x4 h4 = __builtin_elementwise_max(uu + vcv, zero4);
            uint2 st;
            st.x = pk2(h4[0], h4[1]);
            st.y = pk2(h4[2], h4[3]);
            const int si = row * 256 + ((c4 * 4) ^ ((row & 7) << 3));
            *reinterpret_cast<uint2*>(&hT[si]) = st;
        }
    }
    __syncthreads();                        // hT ready

    // ---- MFMA: r = h @ W2 + b2 (bias via acc init), B streamed from L2 ----
    const int axor  = (l15 & 7) << 3;
    const int arow0 = l15 * 256;

    f32x4 acc[4][4];
    #pragma unroll
    for (int m = 0; m < 4; ++m)
        #pragma unroll
        for (int n = 0; n < 4; ++n)
            acc[m][n] = (f32x4){b2c[n], b2c[n], b2c[n], b2c[n]};

    #pragma unroll
    for (int kk = 0; kk < 8; ++kk) {
        const int koff = kk * 32 + g * 8;
        s16x8 bfr[4];
        #pragma unroll
        for (int n = 0; n < 4; ++n)
            bfr[n] = *(const s16x8*)&w2s[(wave << 14) + ((kk * 4 + n) << 9) + (lane << 3)];
        s16x8 afr[4];
        #pragma unroll
        for (int m = 0; m < 4; ++m)
            afr[m] = *(const s16x8*)&hT[arow0 + m * 4096 + (koff ^ axor)];
        __builtin_amdgcn_s_setprio(1);
        #pragma unroll
        for (int m = 0; m < 4; ++m)
            #pragma unroll
            for (int n = 0; n < 4; ++n)
                acc[m][n] = __builtin_amdgcn_mfma_f32_16x16x32_bf16(
                    afr[m], bfr[n], acc[m][n], 0, 0, 0);
        __builtin_amdgcn_s_setprio(0);
    }

    // ---- epilogue: relu, score partials (pk-fma + DPP) ----
    #pragma unroll
    for (int m = 0; m < 4; ++m)
        #pragma unroll
        for (int n = 0; n < 4; ++n)
            acc[m][n] = __builtin_elementwise_max(acc[m][n], zero4);

    #pragma unroll
    for (int m = 0; m < 4; ++m) {
        f32x4 spv = acc[m][0] * qe[0];
        spv += acc[m][1] * qe[1];
        spv += acc[m][2] * qe[2];
        spv += acc[m][3] * qe[3];
        #pragma unroll
        for (int j = 0; j < 4; ++j) {
            const float sp = rowsum16(spv[j]);
            if (l15 == 0) srowT[m * 16 + g * 4 + j][wave] = sp;
        }
    }
    __syncthreads();                        // srowT ready

    // ---- exp weights + weighted sums + atomics ----
    f32x4 wrowv[4];
    #pragma unroll
    for (int m = 0; m < 4; ++m)
        #pragma unroll
        for (int j = 0; j < 4; ++j) {
            const float4 s4 = *(const float4*)&srowT[m * 16 + g * 4 + j][0];
            wrowv[m][j] = __builtin_amdgcn_exp2f(
                (s4.x + s4.y + s4.z + s4.w) * 1.4426950408889634f);
        }

    const int slot = bid & (NSLOT - 1);
    if (wave == 0) {
        const f32x4 lsv = (wrowv[0] + wrowv[1]) + (wrowv[2] + wrowv[3]);
        float ls = (lsv[0] + lsv[1]) + (lsv[2] + lsv[3]);
        ls += __shfl_xor(ls, 16);
        ls += __shfl_xor(ls, 32);
        if (lane == 0) atomicAdd(&accb[slot * 257 + 256], ls);
    }

    #pragma unroll
    for (int n = 0; n < 4; ++n) {
        f32x4 wvv = wrowv[0] * acc[0][n];
        wvv += wrowv[1] * acc[1][n];
        wvv += wrowv[2] * acc[2][n];
        wvv += wrowv[3] * acc[3][n];
        float wv = (wvv[0] + wvv[1]) + (wvv[2] + wvv[3]);
        wv += __shfl_xor(wv, 16);
        wv += __shfl_xor(wv, 32);
        if (lane < 16) atomicAdd(&accb[slot * 257 + col0 + n * 16 + lane], wv);
    }

    // ---- last-block-done: fused final MLP (k4) ----
    __threadfence();                        // release: my atomics ordered
    if (tid == 0)
        lastFlag = (atomicAdd((int*)&accb[CTR_OFF], 1) == (int)gridDim.x - 1);
    __syncthreads();
    if (!lastFlag) return;

    __threadfence();                        // acquire: invalidate local caches

    // 256-thread f-MLP (R5-proven body): merge slots -> emb -> fh -> out
    const int t = tid;
    {
        float v0 = 0.f, v1 = 0.f, v2 = 0.f, v3 = 0.f, ls = 0.f;
        #pragma unroll 4
        for (int s = 0; s < NSLOT; s += 4) {
            v0 += accb[(s + 0) * 257 + t];
            v1 += accb[(s + 1) * 257 + t];
            v2 += accb[(s + 2) * 257 + t];
            v3 += accb[(s + 3) * 257 + t];
            ls += accb[s * 257 + 256] + accb[(s + 1) * 257 + 256]
                + accb[(s + 2) * 257 + 256] + accb[(s + 3) * 257 + 256];
        }
        emb[t] = (v0 + v1 + v2 + v3) / ls;
    }
    __syncthreads();

    {
        float h0 = f_b1[t], h1 = 0.f, h2 = 0.f, h3 = 0.f;
        #pragma unroll 8
        for (int k = 0; k < 256; k += 4) {
            h0 += emb[k + 0] * f_w1[(k + 0) * 256 + t];
            h1 += emb[k + 1] * f_w1[(k + 1) * 256 + t];
            h2 += emb[k + 2] * f_w1[(k + 2) * 256 + t];
            h3 += emb[k + 3] * f_w1[(k + 3) * 256 + t];
        }
        fh[t] = fmaxf((h0 + h1) + (h2 + h3), 0.f);
    }
    __syncthreads();

    if (t < 64) {
        float o0 = f_b2[t], o1 = 0.f, o2 = 0.f, o3 = 0.f;
        #pragma unroll 8
        for (int k = 0; k < 256; k += 4) {
            o0 += fh[k + 0] * f_w2[(k + 0) * 64 + t];
            o1 += fh[k + 1] * f_w2[(k + 1) * 64 + t];
            o2 += fh[k + 2] * f_w2[(k + 2) * 64 + t];
            o3 += fh[k + 3] * f_w2[(k + 3) * 64 + t];
        }
        out[t] = (o0 + o1) + (o2 + o3);
    }
}

extern "C" void kernel_launch(void* const* d_in, const int* in_sizes, int n_in,
                              void* d_out, int out_size, void* d_ws, size_t ws_size,
                              hipStream_t stream) {
    const float* x     = (const float*)d_in[0];
    const float* q     = (const float*)d_in[1];
    const float* g_w1  = (const float*)d_in[2];
    const float* g_b1  = (const float*)d_in[3];
    const float* g_w2  = (const float*)d_in[4];
    const float* g_b2  = (const float*)d_in[5];
    const float* qe_w1 = (const float*)d_in[6];
    const float* qe_b1 = (const float*)d_in[7];
    const float* qe_w2 = (const float*)d_in[8];
    const float* qe_b2 = (const float*)d_in[9];
    const float* f_w1  = (const float*)d_in[10];
    const float* f_b1  = (const float*)d_in[11];
    const float* f_w2  = (const float*)d_in[12];
    const float* f_b2  = (const float*)d_in[13];

    float* wsf  = (float*)d_ws;
    float* U    = wsf;                     // 512*256 f32
    float* V    = wsf + 131072;            // 512*256 f32
    float* c0   = wsf + 262144;            // 256
    float* qexp = wsf + 262400;            // 256
    short* w2s  = (short*)(wsf + 262656);  // 256*256 bf16 (swizzled)
    float* accb = wsf + 295424;            // NSLOT slots * 257 floats + counter

    hipLaunchKernelGGL(rn_k1, dim3(114), dim3(256), 0, stream,
                       x, q, g_w1, g_b1, g_w2, qe_w1, qe_b1, qe_w2, qe_b2,
                       U, V, c0, qexp, w2s, accb);
    hipLaunchKernelGGL(rn_k2, dim3(4096), dim3(256), 0, stream,
                       U, V, c0, qexp, (const short*)w2s, g_b2, accb,
                       f_w1, f_b1, f_w2, f_b2, (float*)d_out);
}

// Round 18
// 92.303 us; speedup vs baseline: 3.3775x; 3.3775x over previous
//
#include <hip/hip_runtime.h>
#include <hip/hip_bf16.h>

typedef __attribute__((ext_vector_type(8))) short s16x8;
typedef __attribute__((ext_vector_type(4))) float f32x4;

#define NSLOT 128
#define CTR_OFF (NSLOT * 257)              // completion counter (int) after slots

__device__ __forceinline__ short f2bf(float f) {
    union { float f; unsigned u; } c; c.f = f;
    unsigned u = c.u;
    return (short)((u + 0x7fffu + ((u >> 16) & 1u)) >> 16);  // RNE
}
__device__ __forceinline__ unsigned pk2(float lo, float hi) {
    __hip_bfloat162 p = __float22bfloat162_rn(make_float2(lo, hi));
    return *reinterpret_cast<unsigned*>(&p);
}
// sum over the 16-lane DPP row via row_ror butterfly (VALU only, no DS pipe)
__device__ __forceinline__ float rowsum16(float x) {
    union { float f; int i; } a, b;
    a.f = x;
    b.i = __builtin_amdgcn_mov_dpp(a.i, 0x121, 0xf, 0xf, true); a.f += b.f; // ror:1
    b.i = __builtin_amdgcn_mov_dpp(a.i, 0x122, 0xf, 0xf, true); a.f += b.f; // ror:2
    b.i = __builtin_amdgcn_mov_dpp(a.i, 0x124, 0xf, 0xf, true); a.f += b.f; // ror:4
    b.i = __builtin_amdgcn_mov_dpp(a.i, 0x128, 0xf, 0xf, true); a.f += b.f; // ror:8
    return a.f;
}

// ---------------------------------------------------------------------------
// K1: precompute (unchanged, proven). Also zeroes the completion counter.
// ---------------------------------------------------------------------------
__global__ __launch_bounds__(256) void rn_k1(
    const float* __restrict__ x, const float* __restrict__ q,
    const float* __restrict__ g_w1, const float* __restrict__ g_b1,
    const float* __restrict__ g_w2,
    const float* __restrict__ qe_w1, const float* __restrict__ qe_b1,
    const float* __restrict__ qe_w2, const float* __restrict__ qe_b2,
    float* __restrict__ U, float* __restrict__ V,
    float* __restrict__ c0, float* __restrict__ qexp,
    short* __restrict__ w2s, float* __restrict__ accb)
{
    const int blk = blockIdx.x, t = threadIdx.x;

    if (blk < 64) {
        __shared__ float xs[1024];          // 16 rows x 64
        const int rg = blk >> 1, half = blk & 1;
        const int r0 = rg << 4;
        #pragma unroll
        for (int i = 0; i < 4; ++i) {
            int idx = i * 256 + t;
            xs[idx] = x[(r0 << 6) + idx];
        }
        float w[64];
        #pragma unroll
        for (int k = 0; k < 64; ++k)
            w[k] = g_w1[(half * 64 + k) * 256 + t];
        __syncthreads();
        float* dst = half ? V : U;
        #pragma unroll 2
        for (int r = 0; r < 16; ++r) {
            float a0 = 0.f, a1 = 0.f, a2 = 0.f, a3 = 0.f;
            #pragma unroll
            for (int k = 0; k < 64; k += 4) {
                const float4 xv = *(const float4*)&xs[r * 64 + k];
                a0 += xv.x * w[k + 0];
                a1 += xv.y * w[k + 1];
                a2 += xv.z * w[k + 2];
                a3 += xv.w * w[k + 3];
            }
            dst[(r0 + r) * 256 + t] = (a0 + a1) + (a2 + a3);
        }
    } else if (blk == 64) {
        __shared__ float sbuf[64];
        __shared__ float qh[256];
        if (t < 64) sbuf[t] = q[t];
        __syncthreads();
        float cc = g_b1[t], hh = qe_b1[t];
        #pragma unroll 4
        for (int k = 0; k < 64; ++k) {
            float qv = sbuf[k];
            cc += qv * g_w1[(128 + k) * 256 + t];
            hh += qv * qe_w1[k * 256 + t];
        }
        c0[t] = cc;
        qh[t] = fmaxf(hh, 0.f);
        __syncthreads();
        float qe = qe_b2[t];
        #pragma unroll 4
        for (int k = 0; k < 256; ++k) qe += qh[k] * qe_w2[k * 256 + t];
        qexp[t] = fmaxf(qe, 0.f);
    } else if (blk < 97) {
        const int S0 = (blk - 65) * 2048 + t * 8;
        const float4 wA = *(const float4*)&g_w2[S0];
        const float4 wB = *(const float4*)&g_w2[S0 + 4];
        float wv8[8] = {wA.x, wA.y, wA.z, wA.w, wB.x, wB.y, wB.z, wB.w};
        #pragma unroll
        for (int i = 0; i < 8; ++i) {
            const int S = S0 + i;
            const int k = S >> 8, col = S & 255;
            const int wv = col >> 6, n = (col >> 4) & 3, l15 = col & 15;
            const int kk = k >> 5, g = (k >> 3) & 3, e = k & 7;
            const int lane = g * 16 + l15;
            w2s[((((wv * 8 + kk) * 4 + n) * 64 + lane) << 3) + e] = f2bf(wv8[i]);
        }
    } else {
        const int total = NSLOT * 257 + 1;  // slots + completion counter
        int off = (blk - 97) * 2048 + t * 8;
        #pragma unroll
        for (int i = 0; i < 8; ++i)
            if (off + i < total) accb[off + i] = 0.f;
    }
}

// ---------------------------------------------------------------------------
// K2: R16 body (4096 blocks, 1 unit, launch_bounds(256,4), XOR-swizzled hT,
// 2 barriers, per-unit atomics, packed math) + FUSED FINAL MLP with CHEAP
// RELEASE: accb is only written by device-scope atomics (already executed at
// the coherence point past L2), so release-ordering needs only vmcnt(0) —
// NOT the agent-scope threadfence (whose per-block L2 writeback caused R17's
// 5.6x regression). Acquire threadfence runs in the ONE last block only.
// ---------------------------------------------------------------------------
__global__ __launch_bounds__(256, 4) void rn_k2(
    const float* __restrict__ U, const float* __restrict__ V,
    const float* __restrict__ c0, const float* __restrict__ qexp,
    const short* __restrict__ w2s, const float* __restrict__ g_b2,
    float* __restrict__ accb,
    const float* __restrict__ f_w1, const float* __restrict__ f_b1,
    const float* __restrict__ f_w2, const float* __restrict__ f_b2,
    float* __restrict__ out)
{
    __shared__ short hT[16384];            // 32KB, XOR-swizzled image
    __shared__ float srowT[64][4];         // [row][wave]
    __shared__ float emb[256];
    __shared__ float fh[256];
    __shared__ int   lastFlag;

    const int bid = blockIdx.x;
    const int a   = bid >> 3;
    const int b0  = (bid & 7) << 6;
    const int tid = threadIdx.x;
    const int wave = tid >> 6, lane = tid & 63;
    const int l15 = lane & 15, g = lane >> 4;
    const int col0 = wave << 6;

    const f32x4 zero4 = (f32x4){0.f, 0.f, 0.f, 0.f};

    float qe[4], b2c[4];
    #pragma unroll
    for (int n = 0; n < 4; ++n) {
        int col = col0 + n * 16 + l15;
        qe[n]  = qexp[col];
        b2c[n] = g_b2[col];
    }

    // ---- build h tile: 64 rows x 256 cols (bf16, swizzled) ----
    {
        const int c4 = tid & 63;
        const int r0 = tid >> 6;
        const f32x4 vv  = *(const f32x4*)&V[a * 256 + c4 * 4];
        const f32x4 cc  = *(const f32x4*)&c0[c4 * 4];
        const f32x4 vcv = vv + cc;
        #pragma unroll
        for (int it = 0; it < 16; ++it) {
            const int row = r0 + it * 4;
            const f32x4 uu = *(const f32x4*)&U[(b0 + row) * 256 + c4 * 4];
            const f32x4 h4 = __builtin_elementwise_max(uu + vcv, zero4);
            uint2 st;
            st.x = pk2(h4[0], h4[1]);
            st.y = pk2(h4[2], h4[3]);
            const int si = row * 256 + ((c4 * 4) ^ ((row & 7) << 3));
            *reinterpret_cast<uint2*>(&hT[si]) = st;
        }
    }
    __syncthreads();                        // hT ready

    // ---- MFMA: r = h @ W2 + b2 (bias via acc init), B streamed from L2 ----
    const int axor  = (l15 & 7) << 3;
    const int arow0 = l15 * 256;

    f32x4 acc[4][4];
    #pragma unroll
    for (int m = 0; m < 4; ++m)
        #pragma unroll
        for (int n = 0; n < 4; ++n)
            acc[m][n] = (f32x4){b2c[n], b2c[n], b2c[n], b2c[n]};

    #pragma unroll
    for (int kk = 0; kk < 8; ++kk) {
        const int koff = kk * 32 + g * 8;
        s16x8 bfr[4];
        #pragma unroll
        for (int n = 0; n < 4; ++n)
            bfr[n] = *(const s16x8*)&w2s[(wave << 14) + ((kk * 4 + n) << 9) + (lane << 3)];
        s16x8 afr[4];
        #pragma unroll
        for (int m = 0; m < 4; ++m)
            afr[m] = *(const s16x8*)&hT[arow0 + m * 4096 + (koff ^ axor)];
        __builtin_amdgcn_s_setprio(1);
        #pragma unroll
        for (int m = 0; m < 4; ++m)
            #pragma unroll
            for (int n = 0; n < 4; ++n)
                acc[m][n] = __builtin_amdgcn_mfma_f32_16x16x32_bf16(
                    afr[m], bfr[n], acc[m][n], 0, 0, 0);
        __builtin_amdgcn_s_setprio(0);
    }

    // ---- epilogue: relu, score partials (pk-fma + DPP) ----
    #pragma unroll
    for (int m = 0; m < 4; ++m)
        #pragma unroll
        for (int n = 0; n < 4; ++n)
            acc[m][n] = __builtin_elementwise_max(acc[m][n], zero4);

    #pragma unroll
    for (int m = 0; m < 4; ++m) {
        f32x4 spv = acc[m][0] * qe[0];
        spv += acc[m][1] * qe[1];
        spv += acc[m][2] * qe[2];
        spv += acc[m][3] * qe[3];
        #pragma unroll
        for (int j = 0; j < 4; ++j) {
            const float sp = rowsum16(spv[j]);
            if (l15 == 0) srowT[m * 16 + g * 4 + j][wave] = sp;
        }
    }
    __syncthreads();                        // srowT ready

    // ---- exp weights + weighted sums + atomics ----
    f32x4 wrowv[4];
    #pragma unroll
    for (int m = 0; m < 4; ++m)
        #pragma unroll
        for (int j = 0; j < 4; ++j) {
            const float4 s4 = *(const float4*)&srowT[m * 16 + g * 4 + j][0];
            wrowv[m][j] = __builtin_amdgcn_exp2f(
                (s4.x + s4.y + s4.z + s4.w) * 1.4426950408889634f);
        }

    const int slot = bid & (NSLOT - 1);
    if (wave == 0) {
        const f32x4 lsv = (wrowv[0] + wrowv[1]) + (wrowv[2] + wrowv[3]);
        float ls = (lsv[0] + lsv[1]) + (lsv[2] + lsv[3]);
        ls += __shfl_xor(ls, 16);
        ls += __shfl_xor(ls, 32);
        if (lane == 0) atomicAdd(&accb[slot * 257 + 256], ls);
    }

    #pragma unroll
    for (int n = 0; n < 4; ++n) {
        f32x4 wvv = wrowv[0] * acc[0][n];
        wvv += wrowv[1] * acc[1][n];
        wvv += wrowv[2] * acc[2][n];
        wvv += wrowv[3] * acc[3][n];
        float wv = (wvv[0] + wvv[1]) + (wvv[2] + wvv[3]);
        wv += __shfl_xor(wv, 16);
        wv += __shfl_xor(wv, 32);
        if (lane < 16) atomicAdd(&accb[slot * 257 + col0 + n * 16 + lane], wv);
    }

    // ---- last-block-done: fused final MLP (cheap release) ----
    // Slot atomics are device-scope (executed at the coherence point past
    // L2); vmcnt(0) guarantees they are globally visible before the counter
    // increment. No L2 writeback needed -> no per-block threadfence.
    asm volatile("s_waitcnt vmcnt(0)" ::: "memory");
    if (tid == 0)
        lastFlag = (atomicAdd((int*)&accb[CTR_OFF], 1) == (int)gridDim.x - 1);
    __syncthreads();
    if (!lastFlag) return;

    __threadfence();                        // acquire (one block only)

    const int t = tid;
    {
        float v0 = 0.f, v1 = 0.f, v2 = 0.f, v3 = 0.f, ls = 0.f;
        #pragma unroll 4
        for (int s = 0; s < NSLOT; s += 4) {
            v0 += accb[(s + 0) * 257 + t];
            v1 += accb[(s + 1) * 257 + t];
            v2 += accb[(s + 2) * 257 + t];
            v3 += accb[(s + 3) * 257 + t];
            ls += accb[s * 257 + 256] + accb[(s + 1) * 257 + 256]
                + accb[(s + 2) * 257 + 256] + accb[(s + 3) * 257 + 256];
        }
        emb[t] = (v0 + v1 + v2 + v3) / ls;
    }
    __syncthreads();

    {
        float h0 = f_b1[t], h1 = 0.f, h2 = 0.f, h3 = 0.f;
        #pragma unroll 8
        for (int k = 0; k < 256; k += 4) {
            h0 += emb[k + 0] * f_w1[(k + 0) * 256 + t];
            h1 += emb[k + 1] * f_w1[(k + 1) * 256 + t];
            h2 += emb[k + 2] * f_w1[(k + 2) * 256 + t];
            h3 += emb[k + 3] * f_w1[(k + 3) * 256 + t];
        }
        fh[t] = fmaxf((h0 + h1) + (h2 + h3), 0.f);
    }
    __syncthreads();

    if (t < 64) {
        float o0 = f_b2[t], o1 = 0.f, o2 = 0.f, o3 = 0.f;
        #pragma unroll 8
        for (int k = 0; k < 256; k += 4) {
            o0 += fh[k + 0] * f_w2[(k + 0) * 64 + t];
            o1 += fh[k + 1] * f_w2[(k + 1) * 64 + t];
            o2 += fh[k + 2] * f_w2[(k + 2) * 64 + t];
            o3 += fh[k + 3] * f_w2[(k + 3) * 64 + t];
        }
        out[t] = (o0 + o1) + (o2 + o3);
    }
}

extern "C" void kernel_launch(void* const* d_in, const int* in_sizes, int n_in,
                              void* d_out, int out_size, void* d_ws, size_t ws_size,
                              hipStream_t stream) {
    const float* x     = (const float*)d_in[0];
    const float* q     = (const float*)d_in[1];
    const float* g_w1  = (const float*)d_in[2];
    const float* g_b1  = (const float*)d_in[3];
    const float* g_w2  = (const float*)d_in[4];
    const float* g_b2  = (const float*)d_in[5];
    const float* qe_w1 = (const float*)d_in[6];
    const float* qe_b1 = (const float*)d_in[7];
    const float* qe_w2 = (const float*)d_in[8];
    const float* qe_b2 = (const float*)d_in[9];
    const float* f_w1  = (const float*)d_in[10];
    const float* f_b1  = (const float*)d_in[11];
    const float* f_w2  = (const float*)d_in[12];
    const float* f_b2  = (const float*)d_in[13];

    float* wsf  = (float*)d_ws;
    float* U    = wsf;                     // 512*256 f32
    float* V    = wsf + 131072;            // 512*256 f32
    float* c0   = wsf + 262144;            // 256
    float* qexp = wsf + 262400;            // 256
    short* w2s  = (short*)(wsf + 262656);  // 256*256 bf16 (swizzled)
    float* accb = wsf + 295424;            // NSLOT slots * 257 floats + counter

    hipLaunchKernelGGL(rn_k1, dim3(114), dim3(256), 0, stream,
                       x, q, g_w1, g_b1, g_w2, qe_w1, qe_b1, qe_w2, qe_b2,
                       U, V, c0, qexp, w2s, accb);
    hipLaunchKernelGGL(rn_k2, dim3(4096), dim3(256), 0, stream,
                       U, V, c0, qexp, (const short*)w2s, g_b2, accb,
                       f_w1, f_b1, f_w2, f_b2, (float*)d_out);
}

// Round 19
// 66.880 us; speedup vs baseline: 4.6614x; 1.3801x over previous
//
#include <hip/hip_runtime.h>
#include <hip/hip_bf16.h>

typedef __attribute__((ext_vector_type(8))) short s16x8;
typedef __attribute__((ext_vector_type(4))) float f32x4;

#define NSLOT 128

__device__ __forceinline__ short f2bf(float f) {
    union { float f; unsigned u; } c; c.f = f;
    unsigned u = c.u;
    return (short)((u + 0x7fffu + ((u >> 16) & 1u)) >> 16);  // RNE
}
__device__ __forceinline__ unsigned pk2(float lo, float hi) {
    __hip_bfloat162 p = __float22bfloat162_rn(make_float2(lo, hi));
    return *reinterpret_cast<unsigned*>(&p);
}
// sum over the 16-lane DPP row via row_ror butterfly (VALU only, no DS pipe)
__device__ __forceinline__ float rowsum16(float x) {
    union { float f; int i; } a, b;
    a.f = x;
    b.i = __builtin_amdgcn_mov_dpp(a.i, 0x121, 0xf, 0xf, true); a.f += b.f; // ror:1
    b.i = __builtin_amdgcn_mov_dpp(a.i, 0x122, 0xf, 0xf, true); a.f += b.f; // ror:2
    b.i = __builtin_amdgcn_mov_dpp(a.i, 0x124, 0xf, 0xf, true); a.f += b.f; // ror:4
    b.i = __builtin_amdgcn_mov_dpp(a.i, 0x128, 0xf, 0xf, true); a.f += b.f; // ror:8
    return a.f;
}

// ---------------------------------------------------------------------------
// K1: precompute (proven).
//   blocks 0..63:   UV GEMM (W1 col-slice in regs, x-tile in LDS)
//   block 64:       c0 = q@W1q + g_b1 ; q_exp = relu(relu(q@qe_w1+b1)@qe_w2+b2)
//   blocks 65..96:  w2s swizzle (coalesced reads, scatter bf16 writes)
//   blocks 97..113: zero accb
// ---------------------------------------------------------------------------
__global__ __launch_bounds__(256) void rn_k1(
    const float* __restrict__ x, const float* __restrict__ q,
    const float* __restrict__ g_w1, const float* __restrict__ g_b1,
    const float* __restrict__ g_w2,
    const float* __restrict__ qe_w1, const float* __restrict__ qe_b1,
    const float* __restrict__ qe_w2, const float* __restrict__ qe_b2,
    float* __restrict__ U, float* __restrict__ V,
    float* __restrict__ c0, float* __restrict__ qexp,
    short* __restrict__ w2s, float* __restrict__ accb)
{
    const int blk = blockIdx.x, t = threadIdx.x;

    if (blk < 64) {
        __shared__ float xs[1024];          // 16 rows x 64
        const int rg = blk >> 1, half = blk & 1;
        const int r0 = rg << 4;
        #pragma unroll
        for (int i = 0; i < 4; ++i) {
            int idx = i * 256 + t;
            xs[idx] = x[(r0 << 6) + idx];
        }
        float w[64];
        #pragma unroll
        for (int k = 0; k < 64; ++k)
            w[k] = g_w1[(half * 64 + k) * 256 + t];
        __syncthreads();
        float* dst = half ? V : U;
        #pragma unroll 2
        for (int r = 0; r < 16; ++r) {
            float a0 = 0.f, a1 = 0.f, a2 = 0.f, a3 = 0.f;
            #pragma unroll
            for (int k = 0; k < 64; k += 4) {
                const float4 xv = *(const float4*)&xs[r * 64 + k];
                a0 += xv.x * w[k + 0];
                a1 += xv.y * w[k + 1];
                a2 += xv.z * w[k + 2];
                a3 += xv.w * w[k + 3];
            }
            dst[(r0 + r) * 256 + t] = (a0 + a1) + (a2 + a3);
        }
    } else if (blk == 64) {
        __shared__ float sbuf[64];
        __shared__ float qh[256];
        if (t < 64) sbuf[t] = q[t];
        __syncthreads();
        float cc = g_b1[t], hh = qe_b1[t];
        #pragma unroll 4
        for (int k = 0; k < 64; ++k) {
            float qv = sbuf[k];
            cc += qv * g_w1[(128 + k) * 256 + t];
            hh += qv * qe_w1[k * 256 + t];
        }
        c0[t] = cc;
        qh[t] = fmaxf(hh, 0.f);
        __syncthreads();
        float qe = qe_b2[t];
        #pragma unroll 4
        for (int k = 0; k < 256; ++k) qe += qh[k] * qe_w2[k * 256 + t];
        qexp[t] = fmaxf(qe, 0.f);
    } else if (blk < 97) {
        const int S0 = (blk - 65) * 2048 + t * 8;
        const float4 wA = *(const float4*)&g_w2[S0];
        const float4 wB = *(const float4*)&g_w2[S0 + 4];
        float wv8[8] = {wA.x, wA.y, wA.z, wA.w, wB.x, wB.y, wB.z, wB.w};
        #pragma unroll
        for (int i = 0; i < 8; ++i) {
            const int S = S0 + i;
            const int k = S >> 8, col = S & 255;
            const int wv = col >> 6, n = (col >> 4) & 3, l15 = col & 15;
            const int kk = k >> 5, g = (k >> 3) & 3, e = k & 7;
            const int lane = g * 16 + l15;
            w2s[((((wv * 8 + kk) * 4 + n) * 64 + lane) << 3) + e] = f2bf(wv8[i]);
        }
    } else {
        const int total = NSLOT * 257;
        int off = (blk - 97) * 2048 + t * 8;
        #pragma unroll
        for (int i = 0; i < 8; ++i)
            if (off + i < total) accb[off + i] = 0.f;
    }
}

// ---------------------------------------------------------------------------
// K2: best measured configuration (R16): 4096 blocks, 1 unit,
// launch_bounds(256,4), XOR-swizzled hT (flat 32KB), 2 barriers, per-unit
// atomics, bias-in-acc-init, DPP rowsum, exp2, packed f32x4 VALU.
// ---------------------------------------------------------------------------
__global__ __launch_bounds__(256, 4) void rn_k2(
    const float* __restrict__ U, const float* __restrict__ V,
    const float* __restrict__ c0, const float* __restrict__ qexp,
    const short* __restrict__ w2s, const float* __restrict__ g_b2,
    float* __restrict__ accb)
{
    __shared__ short hT[16384];            // 32KB, XOR-swizzled image
    __shared__ float srowT[64][4];         // [row][wave]

    const int bid = blockIdx.x;
    const int a   = bid >> 3;
    const int b0  = (bid & 7) << 6;
    const int tid = threadIdx.x;
    const int wave = tid >> 6, lane = tid & 63;
    const int l15 = lane & 15, g = lane >> 4;
    const int col0 = wave << 6;

    const f32x4 zero4 = (f32x4){0.f, 0.f, 0.f, 0.f};

    float qe[4], b2c[4];
    #pragma unroll
    for (int n = 0; n < 4; ++n) {
        int col = col0 + n * 16 + l15;
        qe[n]  = qexp[col];
        b2c[n] = g_b2[col];
    }

    // ---- build h tile: 64 rows x 256 cols (bf16, swizzled, packed math) ----
    {
        const int c4 = tid & 63;
        const int r0 = tid >> 6;
        const f32x4 vv  = *(const f32x4*)&V[a * 256 + c4 * 4];
        const f32x4 cc  = *(const f32x4*)&c0[c4 * 4];
        const f32x4 vcv = vv + cc;
        #pragma unroll
        for (int it = 0; it < 16; ++it) {
            const int row = r0 + it * 4;
            const f32x4 uu = *(const f32x4*)&U[(b0 + row) * 256 + c4 * 4];
            const f32x4 h4 = __builtin_elementwise_max(uu + vcv, zero4);
            uint2 st;
            st.x = pk2(h4[0], h4[1]);
            st.y = pk2(h4[2], h4[3]);
            const int si = row * 256 + ((c4 * 4) ^ ((row & 7) << 3));
            *reinterpret_cast<uint2*>(&hT[si]) = st;
        }
    }
    __syncthreads();                        // hT ready

    // ---- MFMA: r = h @ W2 + b2 (bias via acc init), B streamed from L2 ----
    const int axor  = (l15 & 7) << 3;
    const int arow0 = l15 * 256;

    f32x4 acc[4][4];
    #pragma unroll
    for (int m = 0; m < 4; ++m)
        #pragma unroll
        for (int n = 0; n < 4; ++n)
            acc[m][n] = (f32x4){b2c[n], b2c[n], b2c[n], b2c[n]};

    #pragma unroll
    for (int kk = 0; kk < 8; ++kk) {
        const int koff = kk * 32 + g * 8;
        s16x8 bfr[4];
        #pragma unroll
        for (int n = 0; n < 4; ++n)
            bfr[n] = *(const s16x8*)&w2s[(wave << 14) + ((kk * 4 + n) << 9) + (lane << 3)];
        s16x8 afr[4];
        #pragma unroll
        for (int m = 0; m < 4; ++m)
            afr[m] = *(const s16x8*)&hT[arow0 + m * 4096 + (koff ^ axor)];
        __builtin_amdgcn_s_setprio(1);
        #pragma unroll
        for (int m = 0; m < 4; ++m)
            #pragma unroll
            for (int n = 0; n < 4; ++n)
                acc[m][n] = __builtin_amdgcn_mfma_f32_16x16x32_bf16(
                    afr[m], bfr[n], acc[m][n], 0, 0, 0);
        __builtin_amdgcn_s_setprio(0);
    }

    // ---- epilogue: relu, score partials (pk-fma + DPP) ----
    #pragma unroll
    for (int m = 0; m < 4; ++m)
        #pragma unroll
        for (int n = 0; n < 4; ++n)
            acc[m][n] = __builtin_elementwise_max(acc[m][n], zero4);

    #pragma unroll
    for (int m = 0; m < 4; ++m) {
        f32x4 spv = acc[m][0] * qe[0];
        spv += acc[m][1] * qe[1];
        spv += acc[m][2] * qe[2];
        spv += acc[m][3] * qe[3];
        #pragma unroll
        for (int j = 0; j < 4; ++j) {
            const float sp = rowsum16(spv[j]);
            if (l15 == 0) srowT[m * 16 + g * 4 + j][wave] = sp;
        }
    }
    __syncthreads();                        // srowT ready

    // ---- exp weights + weighted sums + atomics ----
    f32x4 wrowv[4];
    #pragma unroll
    for (int m = 0; m < 4; ++m)
        #pragma unroll
        for (int j = 0; j < 4; ++j) {
            const float4 s4 = *(const float4*)&srowT[m * 16 + g * 4 + j][0];
            wrowv[m][j] = __builtin_amdgcn_exp2f(
                (s4.x + s4.y + s4.z + s4.w) * 1.4426950408889634f);
        }

    const int slot = bid & (NSLOT - 1);
    if (wave == 0) {
        const f32x4 lsv = (wrowv[0] + wrowv[1]) + (wrowv[2] + wrowv[3]);
        float ls = (lsv[0] + lsv[1]) + (lsv[2] + lsv[3]);
        ls += __shfl_xor(ls, 16);
        ls += __shfl_xor(ls, 32);           // sum over the 4 g-groups
        if (lane == 0) atomicAdd(&accb[slot * 257 + 256], ls);
    }

    #pragma unroll
    for (int n = 0; n < 4; ++n) {
        f32x4 wvv = wrowv[0] * acc[0][n];
        wvv += wrowv[1] * acc[1][n];
        wvv += wrowv[2] * acc[2][n];
        wvv += wrowv[3] * acc[3][n];
        float wv = (wvv[0] + wvv[1]) + (wvv[2] + wvv[3]);
        wv += __shfl_xor(wv, 16);
        wv += __shfl_xor(wv, 32);
        if (lane < 16) atomicAdd(&accb[slot * 257 + col0 + n * 16 + lane], wv);
    }
}

// ---------------------------------------------------------------------------
// K4: merge NSLOT slots -> embedding -> f MLP -> out[64] (1024 thr, K-split)
// ---------------------------------------------------------------------------
__global__ __launch_bounds__(1024) void rn_k4(
    const float* __restrict__ accb,
    const float* __restrict__ f_w1, const float* __restrict__ f_b1,
    const float* __restrict__ f_w2, const float* __restrict__ f_b2,
    float* __restrict__ out)
{
    __shared__ float part[4][256];
    __shared__ float emb[256];
    __shared__ float fh[256];
    __shared__ float lsa[128];
    const int t   = threadIdx.x;
    const int col = t & 255;
    const int sl  = t >> 8;                 // 0..3

    float v = 0.f;
    #pragma unroll 8
    for (int s = sl; s < NSLOT; s += 4) v += accb[s * 257 + col];
    part[sl][col] = v;
    if (t < 128) lsa[t] = accb[t * 257 + 256];
    __syncthreads();

    if (sl == 0) {
        float ls = 0.f;
        #pragma unroll 8
        for (int s = 0; s < 128; ++s) ls += lsa[s];
        emb[col] = (part[0][col] + part[1][col] + part[2][col] + part[3][col]) / ls;
    }
    __syncthreads();

    {
        float h = 0.f;
        const int k0 = sl << 6;
        #pragma unroll 8
        for (int k = 0; k < 64; ++k)
            h += emb[k0 + k] * f_w1[(k0 + k) * 256 + col];
        part[sl][col] = h;
    }
    __syncthreads();
    if (sl == 0)
        fh[col] = fmaxf(part[0][col] + part[1][col] + part[2][col] + part[3][col]
                        + f_b1[col], 0.f);
    __syncthreads();

    if (t < 256) {
        const int oc = t & 63, ks = t >> 6;
        float o = 0.f;
        const int k0 = ks << 6;
        #pragma unroll 8
        for (int k = 0; k < 64; ++k)
            o += fh[k0 + k] * f_w2[(k0 + k) * 64 + oc];
        part[ks][oc] = o;
    }
    __syncthreads();
    if (t < 64)
        out[t] = part[0][t] + part[1][t] + part[2][t] + part[3][t] + f_b2[t];
}

extern "C" void kernel_launch(void* const* d_in, const int* in_sizes, int n_in,
                              void* d_out, int out_size, void* d_ws, size_t ws_size,
                              hipStream_t stream) {
    const float* x     = (const float*)d_in[0];
    const float* q     = (const float*)d_in[1];
    const float* g_w1  = (const float*)d_in[2];
    const float* g_b1  = (const float*)d_in[3];
    const float* g_w2  = (const float*)d_in[4];
    const float* g_b2  = (const float*)d_in[5];
    const float* qe_w1 = (const float*)d_in[6];
    const float* qe_b1 = (const float*)d_in[7];
    const float* qe_w2 = (const float*)d_in[8];
    const float* qe_b2 = (const float*)d_in[9];
    const float* f_w1  = (const float*)d_in[10];
    const float* f_b1  = (const float*)d_in[11];
    const float* f_w2  = (const float*)d_in[12];
    const float* f_b2  = (const float*)d_in[13];

    float* wsf  = (float*)d_ws;
    float* U    = wsf;                     // 512*256 f32
    float* V    = wsf + 131072;            // 512*256 f32
    float* c0   = wsf + 262144;            // 256
    float* qexp = wsf + 262400;            // 256
    short* w2s  = (short*)(wsf + 262656);  // 256*256 bf16 (swizzled)
    float* accb = wsf + 295424;            // NSLOT slots * 257 floats

    hipLaunchKernelGGL(rn_k1, dim3(114), dim3(256), 0, stream,
                       x, q, g_w1, g_b1, g_w2, qe_w1, qe_b1, qe_w2, qe_b2,
                       U, V, c0, qexp, w2s, accb);
    hipLaunchKernelGGL(rn_k2, dim3(4096), dim3(256), 0, stream,
                       U, V, c0, qexp, (const short*)w2s, g_b2, accb);
    hipLaunchKernelGGL(rn_k4, dim3(1), dim3(1024), 0, stream,
                       accb, f_w1, f_b1, f_w2, f_b2, (float*)d_out);
}